// Round 2
// baseline (543.208 us; speedup 1.0000x reference)
//
#include <hip/hip_runtime.h>
#include <math.h>

#define B_ 32
#define C_ 64
#define L_ 8192
#define M_ 32
#define EMB_ 256
#define HID_ 64

// workspace layout (in floats)
#define OFF_TCS  0          // float2[8192*32]: (cos,sin) at [l*32+f]
#define OFF_XF   524288     // float4[2048*32]: (posRe,posIm,negRe[j],negIm[j]) raw sums
#define OFF_PHI  786432     // float[32*32*4]: (pRe,pIm,nRe,nIm) per (b,mm)
#define OFF_GB   790528     // float[32*64*2]: (1+gamma, beta)
#define OFF_COEF 794624     // float[32*64*4*32]: per (b,c): a(cos),b(sin),cc(altcos),dd(altsin)

__global__ __launch_bounds__(256) void k_trig(float2* __restrict__ tcs) {
    int idx = blockIdx.x * 256 + threadIdx.x;   // 0..262143
    int l = idx >> 5, f = idx & 31;
    int r = (f * l) & (L_ - 1);                  // exact mod-L reduction
    float ang = (float)r * (6.283185307179586f / (float)L_);
    tcs[idx] = make_float2(cosf(ang), sinf(ang));
}

__global__ __launch_bounds__(256) void k_phi(const float* __restrict__ emb,
        const float* __restrict__ Arp, const float* __restrict__ Aip,
        const float* __restrict__ Arn, const float* __restrict__ Ain,
        float* __restrict__ phi) {
    int tid = blockIdx.x * 256 + threadIdx.x;   // 0..4095 == (b*32+mm)*4+cmp
    int b = tid >> 7;
    int mm = (tid >> 2) & 31;
    int cmp = tid & 3;
    const float* A = (cmp == 0) ? Arp : (cmp == 1) ? Aip : (cmp == 2) ? Arn : Ain;
    const float4* e4 = (const float4*)(emb + b * EMB_);
    const float4* a4 = (const float4*)(A + mm * EMB_);
    float acc = 0.f;
    for (int q = 0; q < EMB_ / 4; ++q) {
        float4 ev = e4[q], av = a4[q];
        acc += ev.x * av.x + ev.y * av.y + ev.z * av.z + ev.w * av.w;
    }
    phi[tid] = acc;
}

__global__ __launch_bounds__(128) void k_mlp(const float* __restrict__ emb,
        const float* __restrict__ w1, const float* __restrict__ b1,
        const float* __restrict__ w2, const float* __restrict__ b2,
        float* __restrict__ gb) {
    __shared__ float h[HID_];
    int b = blockIdx.x, t = threadIdx.x;
    if (t < HID_) {
        const float4* e4 = (const float4*)(emb + b * EMB_);
        const float4* w4 = (const float4*)(w1 + t * EMB_);
        float acc = b1[t];
        for (int q = 0; q < EMB_ / 4; ++q) {
            float4 ev = e4[q], wv = w4[q];
            acc += ev.x * wv.x + ev.y * wv.y + ev.z * wv.z + ev.w * wv.w;
        }
        h[t] = acc / (1.f + expf(-acc));   // silu
    }
    __syncthreads();
    float g = b2[t];
    const float4* h4 = (const float4*)h;
    const float4* w4 = (const float4*)(w2 + t * HID_);
    for (int q = 0; q < HID_ / 4; ++q) {
        float4 hv = h4[q], wv = w4[q];
        g += hv.x * wv.x + hv.y * wv.y + hv.z * wv.z + hv.w * wv.w;
    }
    if (t < C_) gb[(b * C_ + t) * 2 + 0] = 1.f + g;
    else        gb[(b * C_ + (t - C_)) * 2 + 1] = g;
}

#define DFT_ROWS 16
__global__ __launch_bounds__(256) void k_dft(const float* __restrict__ x,
        const float2* __restrict__ tcs_g, float4* __restrict__ xf) {
    __shared__ float2 tcs[128][34];     // padded: stride 34 float2
    __shared__ float  xs[DFT_ROWS][132];
    int r0 = blockIdx.x * DFT_ROWS;
    int t = threadIdx.x;
    int f = t & 31, rg = t >> 5;        // 8 row-groups x 32 freqs
    float ec0 = 0, ec1 = 0, oc0 = 0, oc1 = 0, es0 = 0, es1 = 0, os0 = 0, os1 = 0;
    for (int l0 = 0; l0 < L_; l0 += 128) {
        __syncthreads();
        // stage trig chunk: 128 l x 32 f float2 = 2048 float4, coalesced
        const float4* src = (const float4*)(tcs_g + (size_t)l0 * 32);
        #pragma unroll
        for (int q = 0; q < 8; ++q) {
            float4 v = src[t + 256 * q];
            int j = (t + 256 * q) * 2;   // float2 flat index
            int ll = j >> 5, ff = j & 31;
            *(float4*)&tcs[ll][ff] = v;
        }
        // stage x chunk: 16 rows x 128
        {
            int i = t >> 4, c16 = t & 15;
            #pragma unroll
            for (int q = 0; q < 2; ++q) {
                int col4 = q * 16 + c16;
                float4 v = *(const float4*)(x + (size_t)(r0 + i) * L_ + l0 + col4 * 4);
                *(float4*)&xs[i][col4 * 4] = v;
            }
        }
        __syncthreads();
        #pragma unroll 4
        for (int lp = 0; lp < 64; ++lp) {
            float2 t0 = tcs[2 * lp][f];
            float2 t1 = tcs[2 * lp + 1][f];
            float2 xa = *(const float2*)&xs[rg * 2 + 0][2 * lp];
            float2 xb = *(const float2*)&xs[rg * 2 + 1][2 * lp];
            ec0 += xa.x * t0.x; es0 += xa.x * t0.y; oc0 += xa.y * t1.x; os0 += xa.y * t1.y;
            ec1 += xb.x * t0.x; es1 += xb.x * t0.y; oc1 += xb.y * t1.x; os1 += xb.y * t1.y;
        }
    }
    int row0 = r0 + rg * 2;
    // pos: sum x e^{-i th} -> re = e+o, im = -(es+os); neg (bin L/2 - f): re = e-o, im = es-os
    xf[(size_t)(row0 + 0) * 32 + f] = make_float4(ec0 + oc0, -(es0 + os0), ec0 - oc0, es0 - os0);
    xf[(size_t)(row0 + 1) * 32 + f] = make_float4(ec1 + oc1, -(es1 + os1), ec1 - oc1, es1 - os1);
}

__global__ __launch_bounds__(64) void k_mix(const float4* __restrict__ xf,
        const float* __restrict__ wpos, const float* __restrict__ wneg,
        const float* __restrict__ phi, float* __restrict__ coef) {
    __shared__ float xr[64], xi[64];
    int bi = blockIdx.x;
    int b = bi >> 6, rem = bi & 63, mm = rem >> 1, side = rem & 1;
    int o = threadIdx.x;
    int slot = side ? (31 - mm) : mm;   // neg j-index = 31-mm
    float4 v = xf[(size_t)(b * 64 + o) * 32 + slot];
    xr[o] = side ? v.z : v.x;
    xi[o] = side ? v.w : v.y;
    __syncthreads();
    const float* W = side ? wneg : wpos;
    float sre = 0.f, sim = 0.f;
    #pragma unroll 8
    for (int i = 0; i < 64; ++i) {
        float2 w = *(const float2*)&W[((size_t)(i * 64 + o) * 32 + mm) * 2];
        float xri = xr[i], xii = xi[i];
        sre += xri * w.x - xii * w.y;
        sim += xri * w.y + xii * w.x;
    }
    const float* ph = &phi[(b * 32 + mm) * 4 + (side ? 2 : 0)];
    float phr = ph[0], phim = ph[1];
    float Pre = sre * phr - sim * phim;
    float Pim = sre * phim + sim * phr;
    const float invL = 1.f / (float)L_;
    float fac = (slot == 0) ? invL : 2.f * invL;     // DC & Nyquist: factor 1
    float a = fac * Pre;
    float bcoef = (slot == 0) ? 0.f : (side ? 2.f * invL * Pim : -2.f * invL * Pim);
    int comp = side ? 2 : 0;
    coef[((size_t)(b * 64 + o) * 4 + comp) * 32 + slot] = a;
    coef[((size_t)(b * 64 + o) * 4 + comp + 1) * 32 + slot] = bcoef;
}

__global__ __launch_bounds__(256) void k_final(const float* __restrict__ x,
        const float2* __restrict__ tcs, const float* __restrict__ coef,
        const float* __restrict__ gb, const float* __restrict__ lw,
        const float* __restrict__ lb, float* __restrict__ out) {
    __shared__ float  sCoef[64 * 128];
    __shared__ float  sLw[64 * 64];
    __shared__ float2 sGB[64];
    __shared__ float  sLb[64];
    int b = blockIdx.x >> 5;        // 32 l-tiles of 256 per batch
    int tile = blockIdx.x & 31;
    int t = threadIdx.x;
    {
        const float4* src = (const float4*)(coef + (size_t)b * 64 * 128);
        float4* dst = (float4*)sCoef;
        #pragma unroll
        for (int q = 0; q < 8; ++q) dst[t + 256 * q] = src[t + 256 * q];
        const float4* srcw = (const float4*)lw;
        float4* dstw = (float4*)sLw;
        #pragma unroll
        for (int q = 0; q < 4; ++q) dstw[t + 256 * q] = srcw[t + 256 * q];
        if (t < 64) { sGB[t] = ((const float2*)gb)[b * 64 + t]; sLb[t] = lb[t]; }
    }
    int l = tile * 256 + t;
    float csx[32], csy[32];
    const float2* tp = tcs + (size_t)l * 32;
    #pragma unroll
    for (int f = 0; f < 32; ++f) { float2 v = tp[f]; csx[f] = v.x; csy[f] = v.y; }
    float xv[64];
    const float* xb = x + (size_t)b * 64 * L_ + l;
    #pragma unroll
    for (int i = 0; i < 64; ++i) xv[i] = xb[(size_t)i * L_];
    float sign = (l & 1) ? -1.f : 1.f;
    __syncthreads();
    float* ob = out + (size_t)b * 64 * L_ + l;
    for (int c = 0; c < 64; ++c) {
        const float4* cf = (const float4*)(sCoef + c * 128);
        float a1 = 0, a2 = 0, a3 = 0, a4 = 0;
        #pragma unroll
        for (int q = 0; q < 8; ++q) {
            float4 A = cf[q], Bv = cf[q + 8], Cv = cf[q + 16], Dv = cf[q + 24];
            a1 += A.x * csx[4 * q] + A.y * csx[4 * q + 1] + A.z * csx[4 * q + 2] + A.w * csx[4 * q + 3];
            a2 += Bv.x * csy[4 * q] + Bv.y * csy[4 * q + 1] + Bv.z * csy[4 * q + 2] + Bv.w * csy[4 * q + 3];
            a3 += Cv.x * csx[4 * q] + Cv.y * csx[4 * q + 1] + Cv.z * csx[4 * q + 2] + Cv.w * csx[4 * q + 3];
            a4 += Dv.x * csy[4 * q] + Dv.y * csy[4 * q + 1] + Dv.z * csy[4 * q + 2] + Dv.w * csy[4 * q + 3];
        }
        float x1 = (a1 + a2) + sign * (a3 + a4);
        const float4* lwc = (const float4*)(sLw + c * 64);
        float aL = 0;
        #pragma unroll
        for (int q = 0; q < 16; ++q) {
            float4 w = lwc[q];
            aL += w.x * xv[4 * q] + w.y * xv[4 * q + 1] + w.z * xv[4 * q + 2] + w.w * xv[4 * q + 3];
        }
        float2 gbv = sGB[c];
        float v = x1 + (aL + sLb[c]) * gbv.x + gbv.y;
        ob[(size_t)c * L_] = v / (1.f + __expf(-v));
    }
}

extern "C" void kernel_launch(void* const* d_in, const int* in_sizes, int n_in,
                              void* d_out, int out_size, void* d_ws, size_t ws_size,
                              hipStream_t stream) {
    const float* x    = (const float*)d_in[0];
    const float* emb  = (const float*)d_in[1];
    const float* wpos = (const float*)d_in[2];
    const float* wneg = (const float*)d_in[3];
    const float* Arp  = (const float*)d_in[4];
    const float* Aip  = (const float*)d_in[5];
    const float* Arn  = (const float*)d_in[6];
    const float* Ain  = (const float*)d_in[7];
    const float* w1   = (const float*)d_in[8];
    const float* b1   = (const float*)d_in[9];
    const float* w2   = (const float*)d_in[10];
    const float* b2   = (const float*)d_in[11];
    const float* lw   = (const float*)d_in[12];
    const float* lb   = (const float*)d_in[13];
    float* out = (float*)d_out;
    float* ws = (float*)d_ws;
    float2* TCS = (float2*)(ws + OFF_TCS);
    float4* XF  = (float4*)(ws + OFF_XF);
    float* PHI  = ws + OFF_PHI;
    float* GB   = ws + OFF_GB;
    float* COEF = ws + OFF_COEF;

    hipLaunchKernelGGL(k_trig, dim3(1024), dim3(256), 0, stream, TCS);
    hipLaunchKernelGGL(k_phi,  dim3(16),   dim3(256), 0, stream, emb, Arp, Aip, Arn, Ain, PHI);
    hipLaunchKernelGGL(k_mlp,  dim3(32),   dim3(128), 0, stream, emb, w1, b1, w2, b2, GB);
    hipLaunchKernelGGL(k_dft,  dim3(128),  dim3(256), 0, stream, x, TCS, XF);
    hipLaunchKernelGGL(k_mix,  dim3(2048), dim3(64),  0, stream, XF, wpos, wneg, PHI, COEF);
    hipLaunchKernelGGL(k_final,dim3(1024), dim3(256), 0, stream, x, TCS, COEF, GB, lw, lb, out);
}

// Round 3
// 334.312 us; speedup vs baseline: 1.6249x; 1.6249x over previous
//
#include <hip/hip_runtime.h>
#include <math.h>

#define L_ 8192
#define EMB_ 256
#define HID_ 64

// workspace layout (in floats)
#define OFF_T    0           // float[128][8192]  synthesis/analysis trig rows
#define OFF_XFR  1048576     // float[2048][128]  raw DFT sums (atomic-accumulated)
#define OFF_PHI  1310720     // float[32*32*4]    (pRe,pIm,nRe,nIm) per (b,mm)
#define OFF_GB   1314816     // float2[32*64]     (1+gamma, beta)
#define OFF_AF   1318912     // float[32][192][64] fused A matrices
#define OFF_B2   1712128     // float[32*64]      fused bias

// T rows: k<32: cos(2*pi*f*l/L), f=k; 32..63: sin, f=k-32;
// 64..95: cos with f=4096+(k-64) == (-1)^l cos; 96..127: sin with f=4096+(k-96) == (-1)^l sin
__global__ __launch_bounds__(256) void k_trig2(float* __restrict__ T) {
    int idx = blockIdx.x * 256 + threadIdx.x;     // 0..1048575
    int k = idx >> 13, l = idx & 8191;
    int f = (k & 31) + ((k & 64) ? 4096 : 0);
    int r = (f * l) & (L_ - 1);
    float ang = (float)r * (6.283185307179586f / (float)L_);
    T[idx] = (k & 32) ? sinf(ang) : cosf(ang);
}

__global__ __launch_bounds__(256) void k_phi(const float* __restrict__ emb,
        const float* __restrict__ Arp, const float* __restrict__ Aip,
        const float* __restrict__ Arn, const float* __restrict__ Ain,
        float* __restrict__ phi) {
    int tid = blockIdx.x * 256 + threadIdx.x;   // (b*32+mm)*4+cmp
    int b = tid >> 7;
    int mm = (tid >> 2) & 31;
    int cmp = tid & 3;
    const float* A = (cmp == 0) ? Arp : (cmp == 1) ? Aip : (cmp == 2) ? Arn : Ain;
    const float4* e4 = (const float4*)(emb + b * EMB_);
    const float4* a4 = (const float4*)(A + mm * EMB_);
    float acc = 0.f;
    for (int q = 0; q < EMB_ / 4; ++q) {
        float4 ev = e4[q], av = a4[q];
        acc += ev.x * av.x + ev.y * av.y + ev.z * av.z + ev.w * av.w;
    }
    phi[tid] = acc;
}

__global__ __launch_bounds__(128) void k_mlp(const float* __restrict__ emb,
        const float* __restrict__ w1, const float* __restrict__ b1,
        const float* __restrict__ w2, const float* __restrict__ b2,
        float* __restrict__ gb) {
    __shared__ float h[HID_];
    int b = blockIdx.x, t = threadIdx.x;
    if (t < HID_) {
        const float4* e4 = (const float4*)(emb + b * EMB_);
        const float4* w4 = (const float4*)(w1 + t * EMB_);
        float acc = b1[t];
        for (int q = 0; q < EMB_ / 4; ++q) {
            float4 ev = e4[q], wv = w4[q];
            acc += ev.x * wv.x + ev.y * wv.y + ev.z * wv.z + ev.w * wv.w;
        }
        h[t] = acc / (1.f + expf(-acc));
    }
    __syncthreads();
    float g = b2[t];
    const float4* h4 = (const float4*)h;
    const float4* w4 = (const float4*)(w2 + t * HID_);
    for (int q = 0; q < HID_ / 4; ++q) {
        float4 hv = h4[q], wv = w4[q];
        g += hv.x * wv.x + hv.y * wv.y + hv.z * wv.z + hv.w * wv.w;
    }
    if (t < 64) gb[(b * 64 + t) * 2 + 0] = 1.f + g;
    else        gb[(b * 64 + (t - 64)) * 2 + 1] = g;
}

// DFT as GEMM: XFR[row][k'] = sum_l x[row][l] * T[k'][l]
// grid 256 = rowgrp(16, 128 rows) x lseg(16, 512 l); threads 256 = kg(16) x rg(16)
__global__ __launch_bounds__(256) void k_dft(const float* __restrict__ x,
        const float* __restrict__ T, float* __restrict__ xfr) {
    __shared__ float sT[32][192];   // [l][granule*12+e]: granule g holds k'=8g..8g+7
    __shared__ float sX[32][132];   // [l][row]
    int rowgrp = blockIdx.x >> 4;
    int seg = blockIdx.x & 15;
    int r0 = rowgrp * 128;
    int lbase = seg * 512;
    int tid = threadIdx.x;
    int kg = tid & 15, rg = tid >> 4;
    float acc[8][8];
    #pragma unroll
    for (int i = 0; i < 8; ++i)
        #pragma unroll
        for (int j = 0; j < 8; ++j) acc[i][j] = 0.f;

    for (int c0 = 0; c0 < 512; c0 += 32) {
        __syncthreads();
        // stage T chunk transposed: 128 k' x 32 l
        #pragma unroll
        for (int j = 0; j < 4; ++j) {
            int flat = tid + 256 * j;            // float4 index
            int kk = flat >> 3, c4 = flat & 7;
            float4 v = *(const float4*)(T + (size_t)kk * L_ + lbase + c0 + c4 * 4);
            int col = (kk >> 3) * 12 + (kk & 7);
            sT[c4 * 4 + 0][col] = v.x;
            sT[c4 * 4 + 1][col] = v.y;
            sT[c4 * 4 + 2][col] = v.z;
            sT[c4 * 4 + 3][col] = v.w;
        }
        // stage x chunk transposed: 128 rows x 32 l
        #pragma unroll
        for (int j = 0; j < 4; ++j) {
            int flat = tid + 256 * j;
            int rr = flat >> 3, c4 = flat & 7;
            float4 v = *(const float4*)(x + (size_t)(r0 + rr) * L_ + lbase + c0 + c4 * 4);
            sX[c4 * 4 + 0][rr] = v.x;
            sX[c4 * 4 + 1][rr] = v.y;
            sX[c4 * 4 + 2][rr] = v.z;
            sX[c4 * 4 + 3][rr] = v.w;
        }
        __syncthreads();
        #pragma unroll 4
        for (int l = 0; l < 32; ++l) {
            float4 t0 = *(const float4*)&sT[l][kg * 12];
            float4 t1 = *(const float4*)&sT[l][kg * 12 + 4];
            float4 xa = *(const float4*)&sX[l][rg * 8];
            float4 xb = *(const float4*)&sX[l][rg * 8 + 4];
            float tv[8] = {t0.x, t0.y, t0.z, t0.w, t1.x, t1.y, t1.z, t1.w};
            float xv[8] = {xa.x, xa.y, xa.z, xa.w, xb.x, xb.y, xb.z, xb.w};
            #pragma unroll
            for (int rr = 0; rr < 8; ++rr)
                #pragma unroll
                for (int e = 0; e < 8; ++e)
                    acc[rr][e] += xv[rr] * tv[e];
        }
    }
    #pragma unroll
    for (int rr = 0; rr < 8; ++rr) {
        int row = r0 + rg * 8 + rr;
        #pragma unroll
        for (int e = 0; e < 8; ++e)
            atomicAdd(&xfr[(size_t)row * 128 + kg * 8 + e], acc[rr][e]);
    }
}

// mode mixing -> A rows 0..127
__global__ __launch_bounds__(64) void k_mix(const float* __restrict__ xfr,
        const float* __restrict__ wpos, const float* __restrict__ wneg,
        const float* __restrict__ phi, float* __restrict__ afull) {
    __shared__ float xr[64], xi[64];
    int bi = blockIdx.x;
    int b = bi >> 6, rem = bi & 63, mm = rem >> 1, side = rem & 1;
    int o = threadIdx.x;
    int slot = side ? (31 - mm) : mm;
    const float* xb = xfr + (size_t)(b * 64 + o) * 128;
    if (!side) { xr[o] = xb[mm];        xi[o] = -xb[32 + mm]; }
    else       { xr[o] = xb[64 + slot]; xi[o] =  xb[96 + slot]; }
    __syncthreads();
    const float* W = side ? wneg : wpos;
    float sre = 0.f, sim = 0.f;
    #pragma unroll 8
    for (int i = 0; i < 64; ++i) {
        float2 w = *(const float2*)&W[((size_t)(i * 64 + o) * 32 + mm) * 2];
        float xri = xr[i], xii = xi[i];
        sre += xri * w.x - xii * w.y;
        sim += xri * w.y + xii * w.x;
    }
    const float* ph = &phi[(b * 32 + mm) * 4 + (side ? 2 : 0)];
    float phr = ph[0], phim = ph[1];
    float Pre = sre * phr - sim * phim;
    float Pim = sre * phim + sim * phr;
    const float invL = 1.f / (float)L_;
    float fac = (slot == 0) ? invL : 2.f * invL;
    float a = fac * Pre;
    float bcoef = (slot == 0) ? 0.f : (side ? 2.f * invL * Pim : -2.f * invL * Pim);
    int comp = side ? 2 : 0;
    afull[((size_t)b * 192 + comp * 32 + slot) * 64 + o] = a;
    afull[((size_t)b * 192 + (comp + 1) * 32 + slot) * 64 + o] = bcoef;
}

// fold lin_w*(1+gamma) into A rows 128..191, bias2 = lb*(1+gamma)+beta
__global__ __launch_bounds__(256) void k_folda(const float* __restrict__ lw,
        const float* __restrict__ lb, const float* __restrict__ gb,
        float* __restrict__ afull, float* __restrict__ bias2) {
    int b = blockIdx.x, tid = threadIdx.x;
    #pragma unroll
    for (int j = 0; j < 16; ++j) {
        int e = tid + 256 * j;          // 0..4095
        int i = e >> 6, o = e & 63;
        float g1 = gb[(b * 64 + o) * 2];
        afull[((size_t)b * 192 + 128 + i) * 64 + o] = lw[o * 64 + i] * g1;
    }
    if (tid < 64) {
        float g1 = gb[(b * 64 + tid) * 2], be = gb[(b * 64 + tid) * 2 + 1];
        bias2[b * 64 + tid] = lb[tid] * g1 + be;
    }
}

// fused synthesis + linear + FiLM + silu: out[b,c,l] = silu( A[b] (64x192) @ B (192xL) + bias2 )
// B rows: 0..127 = T, 128..191 = x[b]
__global__ __launch_bounds__(256) void k_fuse(const float* __restrict__ x,
        const float* __restrict__ T, const float* __restrict__ afull,
        const float* __restrict__ bias2, float* __restrict__ out) {
    __shared__ float sA[192 * 64];
    __shared__ float sB2[64];
    int b = blockIdx.x >> 5, tile = blockIdx.x & 31;
    int tid = threadIdx.x;
    int tc = tid >> 5, tl = tid & 31;
    {
        const float4* asrc = (const float4*)(afull + (size_t)b * 192 * 64);
        float4* adst = (float4*)sA;
        #pragma unroll
        for (int j = 0; j < 12; ++j) adst[tid + 256 * j] = asrc[tid + 256 * j];
        if (tid < 64) sB2[tid] = bias2[b * 64 + tid];
    }
    __syncthreads();
    int c0 = tc * 8;
    int lg = tile * 256 + tl * 8;
    float acc[8][8];
    #pragma unroll
    for (int i = 0; i < 8; ++i)
        #pragma unroll
        for (int j = 0; j < 8; ++j) acc[i][j] = 0.f;

    const float* Bp = T + lg;
    #pragma unroll 2
    for (int k = 0; k < 128; ++k) {
        float4 b0 = *(const float4*)(Bp + (size_t)k * L_);
        float4 b1 = *(const float4*)(Bp + (size_t)k * L_ + 4);
        float4 a0 = *(const float4*)&sA[k * 64 + c0];
        float4 a1 = *(const float4*)&sA[k * 64 + c0 + 4];
        float av[8] = {a0.x, a0.y, a0.z, a0.w, a1.x, a1.y, a1.z, a1.w};
        float bv[8] = {b0.x, b0.y, b0.z, b0.w, b1.x, b1.y, b1.z, b1.w};
        #pragma unroll
        for (int ci = 0; ci < 8; ++ci)
            #pragma unroll
            for (int lj = 0; lj < 8; ++lj)
                acc[ci][lj] += av[ci] * bv[lj];
    }
    const float* Xp = x + (size_t)b * 64 * L_ + lg;
    #pragma unroll 2
    for (int k = 0; k < 64; ++k) {
        float4 b0 = *(const float4*)(Xp + (size_t)k * L_);
        float4 b1 = *(const float4*)(Xp + (size_t)k * L_ + 4);
        float4 a0 = *(const float4*)&sA[(128 + k) * 64 + c0];
        float4 a1 = *(const float4*)&sA[(128 + k) * 64 + c0 + 4];
        float av[8] = {a0.x, a0.y, a0.z, a0.w, a1.x, a1.y, a1.z, a1.w};
        float bv[8] = {b0.x, b0.y, b0.z, b0.w, b1.x, b1.y, b1.z, b1.w};
        #pragma unroll
        for (int ci = 0; ci < 8; ++ci)
            #pragma unroll
            for (int lj = 0; lj < 8; ++lj)
                acc[ci][lj] += av[ci] * bv[lj];
    }
    #pragma unroll
    for (int ci = 0; ci < 8; ++ci) {
        int c = c0 + ci;
        float bias = sB2[c];
        float vbuf[8];
        #pragma unroll
        for (int lj = 0; lj < 8; ++lj) {
            float v = acc[ci][lj] + bias;
            vbuf[lj] = v / (1.f + __expf(-v));
        }
        float* op = out + ((size_t)(b * 64 + c)) * L_ + lg;
        *(float4*)(op)     = *(float4*)&vbuf[0];
        *(float4*)(op + 4) = *(float4*)&vbuf[4];
    }
}

extern "C" void kernel_launch(void* const* d_in, const int* in_sizes, int n_in,
                              void* d_out, int out_size, void* d_ws, size_t ws_size,
                              hipStream_t stream) {
    const float* x    = (const float*)d_in[0];
    const float* emb  = (const float*)d_in[1];
    const float* wpos = (const float*)d_in[2];
    const float* wneg = (const float*)d_in[3];
    const float* Arp  = (const float*)d_in[4];
    const float* Aip  = (const float*)d_in[5];
    const float* Arn  = (const float*)d_in[6];
    const float* Ain  = (const float*)d_in[7];
    const float* w1   = (const float*)d_in[8];
    const float* b1   = (const float*)d_in[9];
    const float* w2   = (const float*)d_in[10];
    const float* b2   = (const float*)d_in[11];
    const float* lw   = (const float*)d_in[12];
    const float* lb   = (const float*)d_in[13];
    float* out = (float*)d_out;
    float* ws = (float*)d_ws;
    float* T    = ws + OFF_T;
    float* XFR  = ws + OFF_XFR;
    float* PHI  = ws + OFF_PHI;
    float* GB   = ws + OFF_GB;
    float* AF   = ws + OFF_AF;
    float* B2   = ws + OFF_B2;

    hipMemsetAsync(XFR, 0, 2048 * 128 * sizeof(float), stream);
    hipLaunchKernelGGL(k_trig2, dim3(4096), dim3(256), 0, stream, T);
    hipLaunchKernelGGL(k_phi,   dim3(16),   dim3(256), 0, stream, emb, Arp, Aip, Arn, Ain, PHI);
    hipLaunchKernelGGL(k_mlp,   dim3(32),   dim3(128), 0, stream, emb, w1, b1, w2, b2, GB);
    hipLaunchKernelGGL(k_dft,   dim3(256),  dim3(256), 0, stream, x, T, XFR);
    hipLaunchKernelGGL(k_mix,   dim3(2048), dim3(64),  0, stream, XFR, wpos, wneg, PHI, AF);
    hipLaunchKernelGGL(k_folda, dim3(32),   dim3(256), 0, stream, lw, lb, GB, AF, B2);
    hipLaunchKernelGGL(k_fuse,  dim3(1024), dim3(256), 0, stream, x, T, AF, B2, out);
}